// Round 3
// baseline (5222.154 us; speedup 1.0000x reference)
//
#include <hip/hip_runtime.h>
#include <cstdint>
#include <cstddef>

// Problem constants
#define B_ 8
#define NT 1024           // query tokens kept
#define NK 1024           // key tokens
#define D_ 768
#define H_ 8
#define HD_ 96
#define CLS_ 20
#define L_ 1044           // CLS_ + NT (full query length in reference)
#define SCALE_ 0.10206207261596577f
#define NEG_ -1e12f

// ---------------------------------------------------------------------------
// JAX threefry2x32, PARTITIONABLE scheme (default in modern JAX):
// for flat element index g, counter pair = (hi, lo) words of 64-bit iota
// = (0, g); 32-bit output = XOR of the two threefry output words.
// key = jax.random.key(42) -> (k0, k1) = (0, 42).
// ---------------------------------------------------------------------------
__device__ __forceinline__ float jax_uniform(uint32_t g) {
    const uint32_t k0 = 0u, k1 = 42u;
    const uint32_t ks2 = k0 ^ k1 ^ 0x1BD11BDAu;
    uint32_t x0 = 0u, x1 = g;

    x0 += k0; x1 += k1;
#define TF_ROUND(r) { x0 += x1; x1 = (x1 << (r)) | (x1 >> (32 - (r))); x1 ^= x0; }
    TF_ROUND(13) TF_ROUND(15) TF_ROUND(26) TF_ROUND(6)
    x0 += k1;  x1 += ks2 + 1u;
    TF_ROUND(17) TF_ROUND(29) TF_ROUND(16) TF_ROUND(24)
    x0 += ks2; x1 += k0 + 2u;
    TF_ROUND(13) TF_ROUND(15) TF_ROUND(26) TF_ROUND(6)
    x0 += k0;  x1 += k1 + 3u;
    TF_ROUND(17) TF_ROUND(29) TF_ROUND(16) TF_ROUND(24)
    x0 += k1;  x1 += ks2 + 4u;
    TF_ROUND(13) TF_ROUND(15) TF_ROUND(26) TF_ROUND(6)
    x0 += ks2; x1 += k0 + 5u;
#undef TF_ROUND
    uint32_t bits = x0 ^ x1;   // partitionable 32-bit output: xor of both words
    return __uint_as_float((bits >> 9) | 0x3F800000u) - 1.0f;
}

// ---------------------------------------------------------------------------
// SGEMM: C[M,N] = A[M,K] @ W[K,N] (+bias). M%64==0, N%64==0, K%16==0 assumed.
// 64x64 tile, BK=16, 256 threads, 4x4 per thread.
// ---------------------------------------------------------------------------
template <bool BIAS>
__global__ __launch_bounds__(256) void sgemm64(
    const float* __restrict__ A, const float* __restrict__ W,
    const float* __restrict__ bias, float* __restrict__ C,
    int M, int N, int K)
{
    __shared__ float As[16][65];   // +1 pad: write conflicts -> 2-way (free)
    __shared__ float Bs[16][64];

    const int tid = threadIdx.x;
    const int bm = blockIdx.y * 64;
    const int bn = blockIdx.x * 64;
    const int tx = tid & 15;        // 0..15
    const int ty = tid >> 4;        // 0..15

    // A-load: thread -> row ar (0..63), k-col ac (0,4,8,12), float4
    const int ar = tid >> 2;
    const int ac = (tid & 3) << 2;
    // B-load: thread -> k-row br (0..15), n-col bc (0..60 step 4), float4
    const int br = tid >> 4;
    const int bc = (tid & 15) << 2;

    float acc[4][4] = {};

    for (int k0 = 0; k0 < K; k0 += 16) {
        float4 av = *(const float4*)&A[(size_t)(bm + ar) * K + k0 + ac];
        float4 bv = *(const float4*)&W[(size_t)(k0 + br) * N + bn + bc];
        As[ac + 0][ar] = av.x;
        As[ac + 1][ar] = av.y;
        As[ac + 2][ar] = av.z;
        As[ac + 3][ar] = av.w;
        *(float4*)&Bs[br][bc] = bv;
        __syncthreads();

#pragma unroll
        for (int kk = 0; kk < 16; ++kk) {
            float a0 = As[kk][ty];
            float a1 = As[kk][ty + 16];
            float a2 = As[kk][ty + 32];
            float a3 = As[kk][ty + 48];
            float b0 = Bs[kk][tx];
            float b1 = Bs[kk][tx + 16];
            float b2 = Bs[kk][tx + 32];
            float b3 = Bs[kk][tx + 48];
            acc[0][0] += a0 * b0; acc[0][1] += a0 * b1; acc[0][2] += a0 * b2; acc[0][3] += a0 * b3;
            acc[1][0] += a1 * b0; acc[1][1] += a1 * b1; acc[1][2] += a1 * b2; acc[1][3] += a1 * b3;
            acc[2][0] += a2 * b0; acc[2][1] += a2 * b1; acc[2][2] += a2 * b2; acc[2][3] += a2 * b3;
            acc[3][0] += a3 * b0; acc[3][1] += a3 * b1; acc[3][2] += a3 * b2; acc[3][3] += a3 * b3;
        }
        __syncthreads();
    }

#pragma unroll
    for (int i = 0; i < 4; ++i) {
#pragma unroll
        for (int j = 0; j < 4; ++j) {
            int r = bm + ty + i * 16;
            int c = bn + tx + j * 16;
            float v = acc[i][j];
            if (BIAS) v += bias[c];
            C[(size_t)r * N + c] = v;
        }
    }
}

// ---------------------------------------------------------------------------
// Attention: one block per (b, h, lq). 256 threads.
//   logits -> split softmax (keys [0,20) and [20,1024)) -> threefry mask ->
//   second softmax -> x = attn @ v
// q  : [B, NT, D]   (head h at column h*HD)
// kv : [B, NK, 1536]  k at col h*96, v at col 768 + h*96
// x  : [B, NT, D]
// ---------------------------------------------------------------------------
__device__ __forceinline__ float block_reduce_max(float v, float* red, int tid) {
    red[tid] = v; __syncthreads();
    for (int s = 128; s > 0; s >>= 1) {
        if (tid < s) red[tid] = fmaxf(red[tid], red[tid + s]);
        __syncthreads();
    }
    float r = red[0]; __syncthreads();
    return r;
}

__device__ __forceinline__ float block_reduce_sum(float v, float* red, int tid) {
    red[tid] = v; __syncthreads();
    for (int s = 128; s > 0; s >>= 1) {
        if (tid < s) red[tid] += red[tid + s];
        __syncthreads();
    }
    float r = red[0]; __syncthreads();
    return r;
}

__global__ __launch_bounds__(256) void attn_kernel(
    const float* __restrict__ q, const float* __restrict__ kv,
    float* __restrict__ x)
{
    const int bid = blockIdx.x;         // b*H*NT + h*NT + lq
    const int lq  = bid & (NT - 1);
    const int h   = (bid >> 10) & (H_ - 1);
    const int b   = bid >> 13;
    const int tid = threadIdx.x;

    __shared__ __align__(16) float sq[HD_];
    __shared__ float sl[NK];
    __shared__ float red[256];
    __shared__ float cstat[2];

    // load q row
    if (tid < HD_) sq[tid] = q[(size_t)(b * NT + lq) * D_ + h * HD_ + tid];
    __syncthreads();

    // ---- logits ----
    const float* kbase = kv + (size_t)b * NK * 1536 + h * HD_;
    for (int n = tid; n < NK; n += 256) {
        const float4* k4 = (const float4*)(kbase + (size_t)n * 1536);
        const float4* q4 = (const float4*)sq;
        float acc = 0.f;
#pragma unroll
        for (int d4 = 0; d4 < HD_ / 4; ++d4) {
            float4 kk = k4[d4];
            float4 qq = q4[d4];
            acc += qq.x * kk.x + qq.y * kk.y + qq.z * kk.z + qq.w * kk.w;
        }
        sl[n] = acc * SCALE_;
    }
    __syncthreads();

    // ---- split softmax: patch part [20, 1024) via block reduce ----
    float lm = -INFINITY;
    for (int n = CLS_ + tid; n < NK; n += 256) lm = fmaxf(lm, sl[n]);
    float pm = block_reduce_max(lm, red, tid);
    float ls = 0.f;
    for (int n = CLS_ + tid; n < NK; n += 256) ls += __expf(sl[n] - pm);
    float ps = block_reduce_sum(ls, red, tid);

    // ---- cls part [0, 20): serial on thread 0 ----
    if (tid == 0) {
        float m = -INFINITY;
        for (int n = 0; n < CLS_; ++n) m = fmaxf(m, sl[n]);
        float s = 0.f;
        for (int n = 0; n < CLS_; ++n) s += __expf(sl[n] - m);
        cstat[0] = m; cstat[1] = s;
    }
    __syncthreads();

    // ---- first-softmax probs + threefry mask ----
    const float inv_ps = 1.f / ps;
    const uint32_t row = (uint32_t)(((b * H_ + h) * L_) + (lq + CLS_));
    for (int n = tid; n < NK; n += 256) {
        float val = sl[n];
        float p = (n < CLS_) ? __expf(val - cstat[0]) / cstat[1]
                             : __expf(val - pm) * inv_ps;
        float u = jax_uniform(row * (uint32_t)NK + (uint32_t)n);
        if (u < 0.3f) p += NEG_;
        sl[n] = p;
    }
    __syncthreads();

    // ---- second softmax over all 1024 ----
    float m2 = -INFINITY;
    for (int n = tid; n < NK; n += 256) m2 = fmaxf(m2, sl[n]);
    float gm = block_reduce_max(m2, red, tid);
    float s2 = 0.f;
    for (int n = tid; n < NK; n += 256) s2 += __expf(sl[n] - gm);
    float gs = block_reduce_sum(s2, red, tid);
    const float inv_gs = 1.f / gs;
    for (int n = tid; n < NK; n += 256) sl[n] = __expf(sl[n] - gm) * inv_gs;
    __syncthreads();

    // ---- x = attn @ v : 2 groups of 96 lanes, each over 512 keys ----
    if (tid < 2 * HD_) {
        const int g = tid / HD_;       // 0 or 1
        const int d = tid % HD_;
        const float* vbase = kv + (size_t)b * NK * 1536 + 768 + h * HD_ + d;
        float acc = 0.f;
        const int n0 = g * (NK / 2), n1 = n0 + NK / 2;
        for (int n = n0; n < n1; ++n) acc += sl[n] * vbase[(size_t)n * 1536];
        red[tid] = acc;
    }
    __syncthreads();
    if (tid < HD_) {
        x[(size_t)(b * NT + lq) * D_ + h * HD_ + tid] = red[tid] + red[HD_ + tid];
    }
}

// ---------------------------------------------------------------------------
extern "C" void kernel_launch(void* const* d_in, const int* in_sizes, int n_in,
                              void* d_out, int out_size, void* d_ws, size_t ws_size,
                              hipStream_t stream)
{
    const float* in_q   = (const float*)d_in[0];  // [8,1024,768]
    const float* in_k   = (const float*)d_in[1];  // [8,1024,768]
    const float* Wq     = (const float*)d_in[2];  // [768,768]
    const float* Wkv    = (const float*)d_in[3];  // [768,1536]
    // d_in[4] = Wcls — unused: cls query rows are dropped by the reference output
    const float* Wproj  = (const float*)d_in[5];  // [768,768]
    const float* bproj  = (const float*)d_in[6];  // [768]
    float* out = (float*)d_out;                   // [8,1024,768]

    float* q  = (float*)d_ws;                     // 8*1024*768  floats
    float* kvb = q  + (size_t)B_ * NT * D_;       // 8*1024*1536 floats
    float* xb  = kvb + (size_t)B_ * NK * 2 * D_;  // 8*1024*768  floats

    dim3 blk(256);

    // q = input_query @ Wq        [8192,768] x [768,768]
    sgemm64<false><<<dim3(D_ / 64, (B_ * NT) / 64), blk, 0, stream>>>(
        in_q, Wq, nullptr, q, B_ * NT, D_, D_);

    // kv = input_key @ Wkv        [8192,768] x [768,1536]
    sgemm64<false><<<dim3((2 * D_) / 64, (B_ * NK) / 64), blk, 0, stream>>>(
        in_k, Wkv, nullptr, kvb, B_ * NK, 2 * D_, D_);

    // attention
    attn_kernel<<<dim3(B_ * H_ * NT), blk, 0, stream>>>(q, kvb, xb);

    // out = x @ Wproj + bproj     [8192,768] x [768,768]
    sgemm64<true><<<dim3(D_ / 64, (B_ * NT) / 64), blk, 0, stream>>>(
        xb, Wproj, bproj, out, B_ * NT, D_, D_);
}

// Round 4
// 2333.739 us; speedup vs baseline: 2.2377x; 2.2377x over previous
//
#include <hip/hip_runtime.h>
#include <cstdint>
#include <cstddef>

// Problem constants
#define B_ 8
#define NT 1024           // query tokens kept
#define NK 1024           // key tokens
#define D_ 768
#define H_ 8
#define HD_ 96
#define CLS_ 20
#define L_ 1044           // CLS_ + NT (full query length in reference)
#define SCALE_ 0.10206207261596577f
#define NEG_ -1e12f
#define TQ 8              // query rows per attention block

// ---------------------------------------------------------------------------
// JAX threefry2x32, partitionable scheme (verified round 3):
// counter = (0, g), output = x0 ^ x1. key = (0, 42).
// ---------------------------------------------------------------------------
__device__ __forceinline__ float jax_uniform(uint32_t g) {
    const uint32_t k0 = 0u, k1 = 42u;
    const uint32_t ks2 = k0 ^ k1 ^ 0x1BD11BDAu;
    uint32_t x0 = 0u, x1 = g;

    x0 += k0; x1 += k1;
#define TF_ROUND(r) { x0 += x1; x1 = (x1 << (r)) | (x1 >> (32 - (r))); x1 ^= x0; }
    TF_ROUND(13) TF_ROUND(15) TF_ROUND(26) TF_ROUND(6)
    x0 += k1;  x1 += ks2 + 1u;
    TF_ROUND(17) TF_ROUND(29) TF_ROUND(16) TF_ROUND(24)
    x0 += ks2; x1 += k0 + 2u;
    TF_ROUND(13) TF_ROUND(15) TF_ROUND(26) TF_ROUND(6)
    x0 += k0;  x1 += k1 + 3u;
    TF_ROUND(17) TF_ROUND(29) TF_ROUND(16) TF_ROUND(24)
    x0 += k1;  x1 += ks2 + 4u;
    TF_ROUND(13) TF_ROUND(15) TF_ROUND(26) TF_ROUND(6)
    x0 += ks2; x1 += k0 + 5u;
#undef TF_ROUND
    uint32_t bits = x0 ^ x1;
    return __uint_as_float((bits >> 9) | 0x3F800000u) - 1.0f;
}

// ---------------------------------------------------------------------------
// SGEMM: C[M,N] = A[M,K] @ W[K,N] (+bias). 64x64 tile, BK=16, 256 thr, 4x4.
// (unchanged from round 3 — ~500us combined; MFMA conversion is a later,
//  isolated experiment)
// ---------------------------------------------------------------------------
template <bool BIAS>
__global__ __launch_bounds__(256) void sgemm64(
    const float* __restrict__ A, const float* __restrict__ W,
    const float* __restrict__ bias, float* __restrict__ C,
    int M, int N, int K)
{
    __shared__ float As[16][65];
    __shared__ float Bs[16][64];

    const int tid = threadIdx.x;
    const int bm = blockIdx.y * 64;
    const int bn = blockIdx.x * 64;
    const int tx = tid & 15;
    const int ty = tid >> 4;

    const int ar = tid >> 2;
    const int ac = (tid & 3) << 2;
    const int br = tid >> 4;
    const int bc = (tid & 15) << 2;

    float acc[4][4] = {};

    for (int k0 = 0; k0 < K; k0 += 16) {
        float4 av = *(const float4*)&A[(size_t)(bm + ar) * K + k0 + ac];
        float4 bv = *(const float4*)&W[(size_t)(k0 + br) * N + bn + bc];
        As[ac + 0][ar] = av.x;
        As[ac + 1][ar] = av.y;
        As[ac + 2][ar] = av.z;
        As[ac + 3][ar] = av.w;
        *(float4*)&Bs[br][bc] = bv;
        __syncthreads();

#pragma unroll
        for (int kk = 0; kk < 16; ++kk) {
            float a0 = As[kk][ty];
            float a1 = As[kk][ty + 16];
            float a2 = As[kk][ty + 32];
            float a3 = As[kk][ty + 48];
            float b0 = Bs[kk][tx];
            float b1 = Bs[kk][tx + 16];
            float b2 = Bs[kk][tx + 32];
            float b3 = Bs[kk][tx + 48];
            acc[0][0] += a0 * b0; acc[0][1] += a0 * b1; acc[0][2] += a0 * b2; acc[0][3] += a0 * b3;
            acc[1][0] += a1 * b0; acc[1][1] += a1 * b1; acc[1][2] += a1 * b2; acc[1][3] += a1 * b3;
            acc[2][0] += a2 * b0; acc[2][1] += a2 * b1; acc[2][2] += a2 * b2; acc[2][3] += a2 * b3;
            acc[3][0] += a3 * b0; acc[3][1] += a3 * b1; acc[3][2] += a3 * b2; acc[3][3] += a3 * b3;
        }
        __syncthreads();
    }

#pragma unroll
    for (int i = 0; i < 4; ++i) {
#pragma unroll
        for (int j = 0; j < 4; ++j) {
            int r = bm + ty + i * 16;
            int c = bn + tx + j * 16;
            float v = acc[i][j];
            if (BIAS) v += bias[c];
            C[(size_t)r * N + c] = v;
        }
    }
}

// ---------------------------------------------------------------------------
// Attention v2: one block per (b, h, 8-query-row tile). 256 threads, 8192 blks.
//   QK as tiled GEMM (K chunks in LDS) -> logits in LDS sP[8][1024] ->
//   shfl-based split softmax -> threefry mask -> 2nd softmax (exp stored
//   unnormalized, 1/s2 folded into PV epilogue) -> PV with V from L2.
// LDS: sQ 3072 + sK 25600 + sP 32768 + rstat 192 = 61632 B (<64K -> 2 blk/CU)
// ---------------------------------------------------------------------------
__global__ __launch_bounds__(256) void attn_kernel(
    const float* __restrict__ q, const float* __restrict__ kv,
    float* __restrict__ x)
{
    const int bid  = blockIdx.x;       // b*8*128 + h*128 + tile
    const int tile = bid & 127;
    const int h    = (bid >> 7) & 7;
    const int b    = bid >> 10;
    const int lq0  = tile * TQ;
    const int tid  = threadIdx.x;

    __shared__ float4 sQ[TQ][24];      // 8 rows x 96 dims
    __shared__ float  sK[64][100];     // 64-key chunk, pad 96->100 (16B-aligned rows)
    __shared__ float  sP[TQ][1024];    // logits -> probs -> exp(p-m2)
    __shared__ float  rstat[6][TQ];    // 0:pm 1:ps 2:cm 3:cs 4:m2 5:s2

    // ---- load Q tile (8 x 96 floats = 192 float4) ----
    if (tid < 192) {
        int r = tid / 24, c = tid % 24;
        sQ[r][c] = *(const float4*)&q[(size_t)(b * NT + lq0 + r) * D_ + h * HD_ + c * 4];
    }
    __syncthreads();

    // ---- QK^T: chunks of 64 keys; thread = (2-row tile, key) ----
    const float* kbase = kv + (size_t)b * NK * 1536 + h * HD_;
    const int key = tid & 63;
    const int rb  = (tid >> 6) * 2;    // wave-uniform row base: 0,2,4,6
    for (int c0 = 0; c0 < NK; c0 += 64) {
        // stage K chunk: 64 rows x 24 float4
        for (int i = tid; i < 1536; i += 256) {
            int kr = i / 24, kc = i % 24;
            *(float4*)&sK[kr][kc * 4] =
                *(const float4*)&kbase[(size_t)(c0 + kr) * 1536 + kc * 4];
        }
        __syncthreads();

        float acc0 = 0.f, acc1 = 0.f;
        const float4* krow = (const float4*)&sK[key][0];
#pragma unroll
        for (int i = 0; i < 24; ++i) {
            float4 kf = krow[i];
            float4 q0 = sQ[rb][i];       // wave-uniform -> LDS broadcast
            float4 q1 = sQ[rb + 1][i];
            acc0 += q0.x * kf.x + q0.y * kf.y + q0.z * kf.z + q0.w * kf.w;
            acc1 += q1.x * kf.x + q1.y * kf.y + q1.z * kf.z + q1.w * kf.w;
        }
        sP[rb][c0 + key]     = acc0 * SCALE_;
        sP[rb + 1][c0 + key] = acc1 * SCALE_;
        __syncthreads();
    }

    // ---- split softmax stats; 32 threads per row ----
    const int r = tid >> 5, s = tid & 31;
    float* row = sP[r];

    float mx = -INFINITY;
    for (int j = 0; j < 32; ++j) {
        int n = s + 32 * j;
        if (n >= CLS_) mx = fmaxf(mx, row[n]);
    }
#pragma unroll
    for (int m = 1; m <= 16; m <<= 1) mx = fmaxf(mx, __shfl_xor(mx, m));
    if (s == 0) rstat[0][r] = mx;
    __syncthreads();

    const float pm = rstat[0][r];
    float sum = 0.f;
    for (int j = 0; j < 32; ++j) {
        int n = s + 32 * j;
        if (n >= CLS_) sum += __expf(row[n] - pm);
    }
#pragma unroll
    for (int m = 1; m <= 16; m <<= 1) sum += __shfl_xor(sum, m);
    if (s == 0) rstat[1][r] = sum;
    if (s == 1) {     // cls stats: 20 elems, serial
        float cm = -INFINITY;
        for (int n = 0; n < CLS_; ++n) cm = fmaxf(cm, row[n]);
        float cs = 0.f;
        for (int n = 0; n < CLS_; ++n) cs += __expf(row[n] - cm);
        rstat[2][r] = cm; rstat[3][r] = cs;
    }
    __syncthreads();

    // ---- first-softmax probs + threefry mask ----
    {
        const float ips = 1.f / rstat[1][r];
        const float cm  = rstat[2][r];
        const float ics = 1.f / rstat[3][r];
        const uint32_t gbase =
            ((uint32_t)(b * H_ + h) * (uint32_t)L_ + (uint32_t)(lq0 + r + CLS_)) * (uint32_t)NK;
        for (int j = 0; j < 32; ++j) {
            int n = s + 32 * j;
            float l = row[n];
            float p = (n < CLS_) ? __expf(l - cm) * ics : __expf(l - pm) * ips;
            float u = jax_uniform(gbase + (uint32_t)n);
            if (u < 0.3f) p += NEG_;
            row[n] = p;
        }
    }
    __syncthreads();

    // ---- 2nd softmax: max, then store unnormalized exp; 1/s2 in epilogue ----
    float mx2 = -INFINITY;
    for (int j = 0; j < 32; ++j) mx2 = fmaxf(mx2, row[s + 32 * j]);
#pragma unroll
    for (int m = 1; m <= 16; m <<= 1) mx2 = fmaxf(mx2, __shfl_xor(mx2, m));
    if (s == 0) rstat[4][r] = mx2;
    __syncthreads();

    const float m2 = rstat[4][r];
    float s2 = 0.f;
    for (int j = 0; j < 32; ++j) {
        int n = s + 32 * j;
        float e = __expf(row[n] - m2);
        row[n] = e;
        s2 += e;
    }
#pragma unroll
    for (int m = 1; m <= 16; m <<= 1) s2 += __shfl_xor(s2, m);
    if (s == 0) rstat[5][r] = s2;
    __syncthreads();

    // ---- PV: 192 threads = 2 row-groups x 96 d-lanes, 4 rows each ----
    if (tid < 192) {
        const int rg = tid / 96;           // 0,1 -> rows rg*4..rg*4+3
        const int d  = tid - rg * 96;
        const float* vbase = kv + (size_t)b * NK * 1536 + 768 + h * HD_ + d;
        const float4* p0 = (const float4*)sP[rg * 4 + 0];
        const float4* p1 = (const float4*)sP[rg * 4 + 1];
        const float4* p2 = (const float4*)sP[rg * 4 + 2];
        const float4* p3 = (const float4*)sP[rg * 4 + 3];
        float a0 = 0.f, a1 = 0.f, a2 = 0.f, a3 = 0.f;
        for (int n4 = 0; n4 < 256; ++n4) {
            float4 f0 = p0[n4], f1 = p1[n4], f2 = p2[n4], f3 = p3[n4];
            const float* vp = vbase + (size_t)(n4 * 4) * 1536;
            float v0 = vp[0];
            float v1 = vp[1536];
            float v2 = vp[3072];
            float v3 = vp[4608];
            a0 += f0.x * v0 + f0.y * v1 + f0.z * v2 + f0.w * v3;
            a1 += f1.x * v0 + f1.y * v1 + f1.z * v2 + f1.w * v3;
            a2 += f2.x * v0 + f2.y * v1 + f2.z * v2 + f2.w * v3;
            a3 += f3.x * v0 + f3.y * v1 + f3.z * v2 + f3.w * v3;
        }
        const size_t obase = (size_t)(b * NT + lq0 + rg * 4) * D_ + h * HD_ + d;
        x[obase + 0 * D_] = a0 * (1.f / rstat[5][rg * 4 + 0]);
        x[obase + 1 * D_] = a1 * (1.f / rstat[5][rg * 4 + 1]);
        x[obase + 2 * D_] = a2 * (1.f / rstat[5][rg * 4 + 2]);
        x[obase + 3 * D_] = a3 * (1.f / rstat[5][rg * 4 + 3]);
    }
}

// ---------------------------------------------------------------------------
extern "C" void kernel_launch(void* const* d_in, const int* in_sizes, int n_in,
                              void* d_out, int out_size, void* d_ws, size_t ws_size,
                              hipStream_t stream)
{
    const float* in_q   = (const float*)d_in[0];  // [8,1024,768]
    const float* in_k   = (const float*)d_in[1];  // [8,1024,768]
    const float* Wq     = (const float*)d_in[2];  // [768,768]
    const float* Wkv    = (const float*)d_in[3];  // [768,1536]
    // d_in[4] = Wcls — unused: cls query rows are dropped by the reference output
    const float* Wproj  = (const float*)d_in[5];  // [768,768]
    const float* bproj  = (const float*)d_in[6];  // [768]
    float* out = (float*)d_out;                   // [8,1024,768]

    float* q   = (float*)d_ws;                    // 8*1024*768  floats
    float* kvb = q   + (size_t)B_ * NT * D_;      // 8*1024*1536 floats
    float* xb  = kvb + (size_t)B_ * NK * 2 * D_;  // 8*1024*768  floats

    dim3 blk(256);

    sgemm64<false><<<dim3(D_ / 64, (B_ * NT) / 64), blk, 0, stream>>>(
        in_q, Wq, nullptr, q, B_ * NT, D_, D_);

    sgemm64<false><<<dim3((2 * D_) / 64, (B_ * NK) / 64), blk, 0, stream>>>(
        in_k, Wkv, nullptr, kvb, B_ * NK, 2 * D_, D_);

    attn_kernel<<<dim3(B_ * H_ * (NT / TQ)), blk, 0, stream>>>(q, kvb, xb);

    sgemm64<true><<<dim3(D_ / 64, (B_ * NT) / 64), blk, 0, stream>>>(
        xb, Wproj, bproj, out, B_ * NT, D_, D_);
}

// Round 5
// 1207.033 us; speedup vs baseline: 4.3264x; 1.9335x over previous
//
#include <hip/hip_runtime.h>
#include <cstdint>
#include <cstddef>

// Problem constants
#define B_ 8
#define NT 1024           // query tokens kept
#define NK 1024           // key tokens
#define D_ 768
#define H_ 8
#define HD_ 96
#define CLS_ 20
#define L_ 1044           // CLS_ + NT (full query length in reference)
#define SCALE_ 0.10206207261596577f
#define NEG_ -1e12f
#define TQ 8              // query rows per attention block

typedef __attribute__((ext_vector_type(8))) short bf16x8;
typedef __attribute__((ext_vector_type(4))) float f32x4;

__device__ __forceinline__ unsigned short f2bf(float f) {
    uint32_t u = __float_as_uint(f);
    u += 0x7FFFu + ((u >> 16) & 1u);   // RNE (no NaN inputs here)
    return (unsigned short)(u >> 16);
}

// ---------------------------------------------------------------------------
// JAX threefry2x32, partitionable scheme (verified round 3):
// counter = (0, g), output = x0 ^ x1. key = (0, 42).
// ---------------------------------------------------------------------------
__device__ __forceinline__ float jax_uniform(uint32_t g) {
    const uint32_t k0 = 0u, k1 = 42u;
    const uint32_t ks2 = k0 ^ k1 ^ 0x1BD11BDAu;
    uint32_t x0 = 0u, x1 = g;

    x0 += k0; x1 += k1;
#define TF_ROUND(r) { x0 += x1; x1 = (x1 << (r)) | (x1 >> (32 - (r))); x1 ^= x0; }
    TF_ROUND(13) TF_ROUND(15) TF_ROUND(26) TF_ROUND(6)
    x0 += k1;  x1 += ks2 + 1u;
    TF_ROUND(17) TF_ROUND(29) TF_ROUND(16) TF_ROUND(24)
    x0 += ks2; x1 += k0 + 2u;
    TF_ROUND(13) TF_ROUND(15) TF_ROUND(26) TF_ROUND(6)
    x0 += k0;  x1 += k1 + 3u;
    TF_ROUND(17) TF_ROUND(29) TF_ROUND(16) TF_ROUND(24)
    x0 += k1;  x1 += ks2 + 4u;
    TF_ROUND(13) TF_ROUND(15) TF_ROUND(26) TF_ROUND(6)
    x0 += ks2; x1 += k0 + 5u;
#undef TF_ROUND
    uint32_t bits = x0 ^ x1;
    return __uint_as_float((bits >> 9) | 0x3F800000u) - 1.0f;
}

// ---------------------------------------------------------------------------
// SGEMM: C[M,N] = A[M,K] @ W[K,N]. 64x64 tile, BK=16, 256 thr, 4x4.
// MODE 0: fp32 out. MODE 1: fp32 out + bias. MODE 2: bf16 out (Cb).
// MODE 3: kv split — c<768 -> bf16 K to Cb[r][c]; c>=768 -> bf16 V
//         transposed into vT[b][h][d][n] (Cv).
// ---------------------------------------------------------------------------
template <int MODE>
__global__ __launch_bounds__(256) void sgemm64(
    const float* __restrict__ A, const float* __restrict__ W,
    const float* __restrict__ bias, float* __restrict__ C,
    unsigned short* __restrict__ Cb, unsigned short* __restrict__ Cv,
    int M, int N, int K)
{
    __shared__ float As[16][65];
    __shared__ float Bs[16][64];

    const int tid = threadIdx.x;
    const int bm = blockIdx.y * 64;
    const int bn = blockIdx.x * 64;
    const int tx = tid & 15;
    const int ty = tid >> 4;

    const int ar = tid >> 2;
    const int ac = (tid & 3) << 2;
    const int br = tid >> 4;
    const int bc = (tid & 15) << 2;

    float acc[4][4] = {};

    for (int k0 = 0; k0 < K; k0 += 16) {
        float4 av = *(const float4*)&A[(size_t)(bm + ar) * K + k0 + ac];
        float4 bv = *(const float4*)&W[(size_t)(k0 + br) * N + bn + bc];
        As[ac + 0][ar] = av.x;
        As[ac + 1][ar] = av.y;
        As[ac + 2][ar] = av.z;
        As[ac + 3][ar] = av.w;
        *(float4*)&Bs[br][bc] = bv;
        __syncthreads();

#pragma unroll
        for (int kk = 0; kk < 16; ++kk) {
            float a0 = As[kk][ty];
            float a1 = As[kk][ty + 16];
            float a2 = As[kk][ty + 32];
            float a3 = As[kk][ty + 48];
            float b0 = Bs[kk][tx];
            float b1 = Bs[kk][tx + 16];
            float b2 = Bs[kk][tx + 32];
            float b3 = Bs[kk][tx + 48];
            acc[0][0] += a0 * b0; acc[0][1] += a0 * b1; acc[0][2] += a0 * b2; acc[0][3] += a0 * b3;
            acc[1][0] += a1 * b0; acc[1][1] += a1 * b1; acc[1][2] += a1 * b2; acc[1][3] += a1 * b3;
            acc[2][0] += a2 * b0; acc[2][1] += a2 * b1; acc[2][2] += a2 * b2; acc[2][3] += a2 * b3;
            acc[3][0] += a3 * b0; acc[3][1] += a3 * b1; acc[3][2] += a3 * b2; acc[3][3] += a3 * b3;
        }
        __syncthreads();
    }

#pragma unroll
    for (int i = 0; i < 4; ++i) {
#pragma unroll
        for (int j = 0; j < 4; ++j) {
            const int r = bm + ty + i * 16;
            const int c = bn + tx + j * 16;
            const float v = acc[i][j];
            if (MODE == 0) {
                C[(size_t)r * N + c] = v;
            } else if (MODE == 1) {
                C[(size_t)r * N + c] = v + bias[c];
            } else if (MODE == 2) {
                Cb[(size_t)r * 768 + c] = f2bf(v);
            } else {  // MODE 3: kv split
                if (c < 768) {
                    Cb[(size_t)r * 768 + c] = f2bf(v);
                } else {
                    const int d  = c - 768;
                    const int hh = d / 96;
                    const int dd = d - hh * 96;
                    const int bb = r >> 10;
                    const int n  = r & 1023;
                    Cv[(((size_t)(bb * 8 + hh)) * 96 + dd) * 1024 + n] = f2bf(v);
                }
            }
        }
    }
}

// ---------------------------------------------------------------------------
// Attention v3: bf16 MFMA QK^T + PV. One block per (b, h, 8-row tile).
// 8192 blocks x 256 threads. LDS: sP 32768 + sPb 16512 + rstat 192 = 49.5 KB
// -> 3 blocks/CU.
// MFMA 16x16x32 bf16 layouts (guide §3, HW-verified m89/m91/m120):
//   A/B: lane holds [row=lane&15][k=quad*8+j] (8 contiguous bf16 = 16 B)
//   C/D: col=lane&15, row=quad*4+reg
// Query rows duplicated (m&7) into rows 8..15; top half of D discarded.
// ---------------------------------------------------------------------------
__global__ __launch_bounds__(256) void attn_kernel(
    const unsigned short* __restrict__ qb, const unsigned short* __restrict__ kb,
    const unsigned short* __restrict__ vT, float* __restrict__ x)
{
    const int bid  = blockIdx.x;       // b*8*128 + h*128 + tile
    const int tile = bid & 127;
    const int h    = (bid >> 7) & 7;
    const int b    = bid >> 10;
    const int lq0  = tile * TQ;
    const int tid  = threadIdx.x;
    const int lane = tid & 63;
    const int wv   = tid >> 6;          // wave 0..3
    const int mcol = lane & 15;
    const int quad = lane >> 4;

    __shared__ __align__(16) float sP[TQ][1024];           // logits -> masked probs
    __shared__ __align__(16) unsigned short sPb[TQ][1032]; // exp(p-m2) bf16 (pad: bank spread)
    __shared__ float rstat[6][TQ];      // 0:pm 1:ps 2:cm 3:cs 4:m2 5:s2

    // ---- QK^T via MFMA: wave wv owns key tiles [wv*16, wv*16+16) ----
    {
        const size_t qrow = ((size_t)(b * NT) + lq0 + (mcol & 7)) * 768 + h * 96 + quad * 8;
        const bf16x8 qa0 = *(const bf16x8*)&qb[qrow];
        const bf16x8 qa1 = *(const bf16x8*)&qb[qrow + 32];
        const bf16x8 qa2 = *(const bf16x8*)&qb[qrow + 64];

        for (int nt = wv * 16; nt < wv * 16 + 16; ++nt) {
            const int n0 = nt * 16;
            const size_t krow = ((size_t)(b * NK) + n0 + mcol) * 768 + h * 96 + quad * 8;
            f32x4 d = {0.f, 0.f, 0.f, 0.f};
            d = __builtin_amdgcn_mfma_f32_16x16x32_bf16(qa0, *(const bf16x8*)&kb[krow],      d, 0, 0, 0);
            d = __builtin_amdgcn_mfma_f32_16x16x32_bf16(qa1, *(const bf16x8*)&kb[krow + 32], d, 0, 0, 0);
            d = __builtin_amdgcn_mfma_f32_16x16x32_bf16(qa2, *(const bf16x8*)&kb[krow + 64], d, 0, 0, 0);
            if (quad < 2) {
#pragma unroll
                for (int rg = 0; rg < 4; ++rg)
                    sP[quad * 4 + rg][n0 + mcol] = d[rg] * SCALE_;
            }
        }
    }
    __syncthreads();

    // ---- split softmax stats; 32 threads per row ----
    const int r = tid >> 5, s = tid & 31;
    float* row = sP[r];

    float mx = -INFINITY;
    for (int j = 0; j < 32; ++j) {
        int n = s + 32 * j;
        if (n >= CLS_) mx = fmaxf(mx, row[n]);
    }
#pragma unroll
    for (int m = 1; m <= 16; m <<= 1) mx = fmaxf(mx, __shfl_xor(mx, m));
    if (s == 0) rstat[0][r] = mx;
    __syncthreads();

    const float pm = rstat[0][r];
    float sum = 0.f;
    for (int j = 0; j < 32; ++j) {
        int n = s + 32 * j;
        if (n >= CLS_) sum += __expf(row[n] - pm);
    }
#pragma unroll
    for (int m = 1; m <= 16; m <<= 1) sum += __shfl_xor(sum, m);
    if (s == 0) rstat[1][r] = sum;
    if (s == 1) {     // cls stats: 20 elems, serial
        float cm = -INFINITY;
        for (int n = 0; n < CLS_; ++n) cm = fmaxf(cm, row[n]);
        float cs = 0.f;
        for (int n = 0; n < CLS_; ++n) cs += __expf(row[n] - cm);
        rstat[2][r] = cm; rstat[3][r] = cs;
    }
    __syncthreads();

    // ---- first-softmax probs + threefry mask ----
    {
        const float ips = 1.f / rstat[1][r];
        const float cm  = rstat[2][r];
        const float ics = 1.f / rstat[3][r];
        const uint32_t gbase =
            ((uint32_t)(b * H_ + h) * (uint32_t)L_ + (uint32_t)(lq0 + r + CLS_)) * (uint32_t)NK;
        for (int j = 0; j < 32; ++j) {
            int n = s + 32 * j;
            float l = row[n];
            float p = (n < CLS_) ? __expf(l - cm) * ics : __expf(l - pm) * ips;
            float u = jax_uniform(gbase + (uint32_t)n);
            if (u < 0.3f) p += NEG_;
            row[n] = p;
        }
    }
    __syncthreads();

    // ---- 2nd softmax: max, then bf16 exp into sPb; 1/s2 folded into PV ----
    float mx2 = -INFINITY;
    for (int j = 0; j < 32; ++j) mx2 = fmaxf(mx2, row[s + 32 * j]);
#pragma unroll
    for (int m = 1; m <= 16; m <<= 1) mx2 = fmaxf(mx2, __shfl_xor(mx2, m));
    if (s == 0) rstat[4][r] = mx2;
    __syncthreads();

    const float m2 = rstat[4][r];
    float s2 = 0.f;
    for (int j = 0; j < 32; ++j) {
        int n = s + 32 * j;
        float e = __expf(row[n] - m2);
        sPb[r][n] = f2bf(e);
        s2 += e;
    }
#pragma unroll
    for (int m = 1; m <= 16; m <<= 1) s2 += __shfl_xor(s2, m);
    if (s == 0) rstat[5][r] = s2;
    __syncthreads();

    // ---- PV via MFMA: wave wv owns d-tiles {wv, wv+4 (if <6)} ----
    {
        const int t0 = wv, t1 = wv + 4;
        const size_t vbase = ((size_t)(b * 8 + h)) * 96 * 1024;
        f32x4 a0 = {0.f, 0.f, 0.f, 0.f};
        f32x4 a1 = {0.f, 0.f, 0.f, 0.f};
        for (int k0 = 0; k0 < 1024; k0 += 32) {
            const bf16x8 pa = *(const bf16x8*)&sPb[mcol & 7][k0 + quad * 8];
            const size_t v0 = vbase + (size_t)(t0 * 16 + mcol) * 1024 + k0 + quad * 8;
            a0 = __builtin_amdgcn_mfma_f32_16x16x32_bf16(pa, *(const bf16x8*)&vT[v0], a0, 0, 0, 0);
            if (t1 < 6) {
                const size_t v1 = vbase + (size_t)(t1 * 16 + mcol) * 1024 + k0 + quad * 8;
                a1 = __builtin_amdgcn_mfma_f32_16x16x32_bf16(pa, *(const bf16x8*)&vT[v1], a1, 0, 0, 0);
            }
        }
        if (quad < 2) {
#pragma unroll
            for (int rg = 0; rg < 4; ++rg) {
                const int rw = quad * 4 + rg;
                const float inv = 1.f / rstat[5][rw];
                const size_t ob = ((size_t)(b * NT) + lq0 + rw) * 768 + h * 96;
                x[ob + t0 * 16 + mcol] = a0[rg] * inv;
                if (t1 < 6) x[ob + t1 * 16 + mcol] = a1[rg] * inv;
            }
        }
    }
}

// ---------------------------------------------------------------------------
extern "C" void kernel_launch(void* const* d_in, const int* in_sizes, int n_in,
                              void* d_out, int out_size, void* d_ws, size_t ws_size,
                              hipStream_t stream)
{
    const float* in_q   = (const float*)d_in[0];  // [8,1024,768]
    const float* in_k   = (const float*)d_in[1];  // [8,1024,768]
    const float* Wq     = (const float*)d_in[2];  // [768,768]
    const float* Wkv    = (const float*)d_in[3];  // [768,1536]
    // d_in[4] = Wcls — unused: cls query rows are dropped by the reference output
    const float* Wproj  = (const float*)d_in[5];  // [768,768]
    const float* bproj  = (const float*)d_in[6];  // [768]
    float* out = (float*)d_out;                   // [8,1024,768]

    float*          xb = (float*)d_ws;                       // 6291456 f32
    unsigned short* qb = (unsigned short*)(xb + 6291456);    // 6291456 bf16
    unsigned short* kb = qb + 6291456;                       // 6291456 bf16
    unsigned short* vT = kb + 6291456;                       // 6291456 bf16 [b][h][96][1024]

    dim3 blk(256);

    // qb = bf16(input_query @ Wq)
    sgemm64<2><<<dim3(D_ / 64, (B_ * NT) / 64), blk, 0, stream>>>(
        in_q, Wq, nullptr, nullptr, qb, nullptr, B_ * NT, D_, D_);

    // kb/vT = bf16(input_key @ Wkv), V transposed per (b,h)
    sgemm64<3><<<dim3((2 * D_) / 64, (B_ * NK) / 64), blk, 0, stream>>>(
        in_k, Wkv, nullptr, nullptr, kb, vT, B_ * NK, 2 * D_, D_);

    // attention (bf16 MFMA)
    attn_kernel<<<dim3(B_ * H_ * (NT / TQ)), blk, 0, stream>>>(qb, kb, vT, xb);

    // out = xb @ Wproj + bproj (fp32)
    sgemm64<1><<<dim3(D_ / 64, (B_ * NT) / 64), blk, 0, stream>>>(
        xb, Wproj, bproj, out, nullptr, nullptr, B_ * NT, D_, D_);
}

// Round 6
// 677.526 us; speedup vs baseline: 7.7077x; 1.7815x over previous
//
#include <hip/hip_runtime.h>
#include <cstdint>
#include <cstddef>

// Problem constants
#define B_ 8
#define NT 1024
#define NK 1024
#define D_ 768
#define H_ 8
#define HD_ 96
#define CLS_ 20
#define L_ 1044
#define SCALE_ 0.10206207261596577f
#define NEG_ -1e12f
#define TQ 8

typedef __attribute__((ext_vector_type(8))) short bf16x8;
typedef __attribute__((ext_vector_type(4))) float f32x4;

__device__ __forceinline__ unsigned short f2bf(float f) {
    uint32_t u = __float_as_uint(f);
    u += 0x7FFFu + ((u >> 16) & 1u);   // RNE (no NaN inputs here)
    return (unsigned short)(u >> 16);
}

// async global->LDS, 16B per lane; LDS dest = wave-uniform base + lane*16
__device__ __forceinline__ void gll16(const void* g, void* l) {
    __builtin_amdgcn_global_load_lds(
        (const __attribute__((address_space(1))) unsigned int*)g,
        (__attribute__((address_space(3))) unsigned int*)l,
        16, 0, 0);
}

// ---------------------------------------------------------------------------
// JAX threefry2x32, partitionable scheme (verified round 3):
// counter = (0, g), output = x0 ^ x1. key = (0, 42).
// ---------------------------------------------------------------------------
__device__ __forceinline__ float jax_uniform(uint32_t g) {
    const uint32_t k0 = 0u, k1 = 42u;
    const uint32_t ks2 = k0 ^ k1 ^ 0x1BD11BDAu;
    uint32_t x0 = 0u, x1 = g;

    x0 += k0; x1 += k1;
#define TF_ROUND(r) { x0 += x1; x1 = (x1 << (r)) | (x1 >> (32 - (r))); x1 ^= x0; }
    TF_ROUND(13) TF_ROUND(15) TF_ROUND(26) TF_ROUND(6)
    x0 += k1;  x1 += ks2 + 1u;
    TF_ROUND(17) TF_ROUND(29) TF_ROUND(16) TF_ROUND(24)
    x0 += ks2; x1 += k0 + 2u;
    TF_ROUND(13) TF_ROUND(15) TF_ROUND(26) TF_ROUND(6)
    x0 += k0;  x1 += k1 + 3u;
    TF_ROUND(17) TF_ROUND(29) TF_ROUND(16) TF_ROUND(24)
    x0 += k1;  x1 += ks2 + 4u;
    TF_ROUND(13) TF_ROUND(15) TF_ROUND(26) TF_ROUND(6)
    x0 += ks2; x1 += k0 + 5u;
#undef TF_ROUND
    uint32_t bits = x0 ^ x1;
    return __uint_as_float((bits >> 9) | 0x3F800000u) - 1.0f;
}

// ---------------------------------------------------------------------------
// fp32 -> bf16 flat convert (float4 granular)
// ---------------------------------------------------------------------------
__global__ __launch_bounds__(256) void conv_bf16(
    const float* __restrict__ src, unsigned short* __restrict__ dst, int n4)
{
    int i = blockIdx.x * 256 + threadIdx.x;
    if (i < n4) {
        float4 v = ((const float4*)src)[i];
        ushort4 o;
        o.x = f2bf(v.x); o.y = f2bf(v.y); o.z = f2bf(v.z); o.w = f2bf(v.w);
        ((ushort4*)dst)[i] = o;
    }
}

// ---------------------------------------------------------------------------
// weight transpose: W[768][Nn] fp32 -> Wt[Nn][768] bf16, 32x32 tiles
// ---------------------------------------------------------------------------
__global__ __launch_bounds__(256) void trw_bf16(
    const float* __restrict__ W, unsigned short* __restrict__ Wt, int Nn)
{
    __shared__ unsigned short tile[32][36];
    const int n0 = blockIdx.x * 32, k0 = blockIdx.y * 32;
    const int t = threadIdx.x, r = t >> 3, c4 = (t & 7) * 4;

    float4 v = *(const float4*)&W[(size_t)(k0 + r) * Nn + n0 + c4];
    tile[r][c4 + 0] = f2bf(v.x);
    tile[r][c4 + 1] = f2bf(v.y);
    tile[r][c4 + 2] = f2bf(v.z);
    tile[r][c4 + 3] = f2bf(v.w);
    __syncthreads();

    ushort4 o;
    o.x = tile[c4 + 0][r];
    o.y = tile[c4 + 1][r];
    o.z = tile[c4 + 2][r];
    o.w = tile[c4 + 3][r];
    *(ushort4*)&Wt[(size_t)(n0 + r) * 768 + k0 + c4] = o;
}

// ---------------------------------------------------------------------------
// V transpose: kv16[8192][1536] bf16 (V half at col 768+h*96) ->
//              vT[(b*8+h)*96 + d][1024] bf16
// block: (b,h,ntile): 64 n-rows x 96 d. Coalesced reads and writes.
// ---------------------------------------------------------------------------
__global__ __launch_bounds__(256) void trv(
    const unsigned short* __restrict__ kv16, unsigned short* __restrict__ vT)
{
    const int bid = blockIdx.x;       // (b*8+h)*16 + nt
    const int nt = bid & 15, bh = bid >> 4;
    const int b = bh >> 3, h = bh & 7;
    const int n0 = nt * 64;
    const int t = threadIdx.x;

    __shared__ unsigned short tile[64][104];   // rows 16B-aligned (208 B)

    for (int i = t; i < 768; i += 256) {       // 64 rows x 12 chunks of 8
        int r = i / 12, c = i % 12;
        *(uint4*)&tile[r][c * 8] =
            *(const uint4*)&kv16[(size_t)(b * 1024 + n0 + r) * 1536 + 768 + h * 96 + c * 8];
    }
    __syncthreads();

    for (int i = t; i < 768; i += 256) {       // 96 d-rows x 8 chunks of 8
        int d = i >> 3, c = i & 7;
        ushort4 lo, hi;
        lo.x = tile[c * 8 + 0][d]; lo.y = tile[c * 8 + 1][d];
        lo.z = tile[c * 8 + 2][d]; lo.w = tile[c * 8 + 3][d];
        hi.x = tile[c * 8 + 4][d]; hi.y = tile[c * 8 + 5][d];
        hi.z = tile[c * 8 + 6][d]; hi.w = tile[c * 8 + 7][d];
        const size_t ob = ((size_t)bh * 96 + d) * 1024 + n0 + c * 8;
        *(ushort4*)&vT[ob]     = lo;
        *(ushort4*)&vT[ob + 4] = hi;
    }
}

// ---------------------------------------------------------------------------
// bf16 MFMA GEMM, NT form: C[M,N] = A[M,K] @ Bt[N,K]^T.
// 128x128 tile, BK=32, 256 threads (4 waves), 4x4 MFMA tiles per wave.
// global_load_lds width-16 staging (m97 pattern).
// MODE 0: bf16 out (Cb). MODE 1: fp32 out + bias, split-A (A + Alo).
// ---------------------------------------------------------------------------
template <int MODE>
__global__ __launch_bounds__(256) void mfma_gemm(
    const unsigned short* __restrict__ A,
    const unsigned short* __restrict__ Alo,
    const unsigned short* __restrict__ Bt,
    const float* __restrict__ bias,
    unsigned short* __restrict__ Cb, float* __restrict__ Cf,
    int N, int K)
{
    __shared__ unsigned short As[128 * 32];
    __shared__ unsigned short Bs[128 * 32];
    __shared__ unsigned short Als[MODE == 1 ? 128 * 32 : 8];

    const int tid  = threadIdx.x;
    const int lane = tid & 63, wv = tid >> 6;
    const int bm = blockIdx.y * 128, bn = blockIdx.x * 128;
    const int mcol = lane & 15, quad = lane >> 4;
    const int wr = (wv & 1) * 64, wc = (wv >> 1) * 64;
    const int srow = lane >> 2;            // 0..15 within segment
    const int skch = (lane & 3) * 8;       // k-chunk 0,8,16,24

    f32x4 acc[4][4];
#pragma unroll
    for (int i = 0; i < 4; ++i)
#pragma unroll
        for (int j = 0; j < 4; ++j) acc[i][j] = (f32x4){0.f, 0.f, 0.f, 0.f};

    for (int k0 = 0; k0 < K; k0 += 32) {
#pragma unroll
        for (int c = 0; c < 2; ++c) {
            const int s = wv * 2 + c;          // segment 0..7 (wave-uniform)
            const int row = s * 16 + srow;
            gll16(&A [(size_t)(bm + row) * K + k0 + skch], &As[s * 512]);
            gll16(&Bt[(size_t)(bn + row) * K + k0 + skch], &Bs[s * 512]);
            if (MODE == 1)
                gll16(&Alo[(size_t)(bm + row) * K + k0 + skch], &Als[s * 512]);
        }
        __syncthreads();

        bf16x8 af[4], bfr[4], al[4];
#pragma unroll
        for (int i = 0; i < 4; ++i) {
            af[i]  = *(const bf16x8*)&As[(wr + i * 16 + mcol) * 32 + quad * 8];
            bfr[i] = *(const bf16x8*)&Bs[(wc + i * 16 + mcol) * 32 + quad * 8];
            if (MODE == 1)
                al[i] = *(const bf16x8*)&Als[(wr + i * 16 + mcol) * 32 + quad * 8];
        }
#pragma unroll
        for (int i = 0; i < 4; ++i)
#pragma unroll
            for (int j = 0; j < 4; ++j) {
                acc[i][j] = __builtin_amdgcn_mfma_f32_16x16x32_bf16(af[i], bfr[j], acc[i][j], 0, 0, 0);
                if (MODE == 1)
                    acc[i][j] = __builtin_amdgcn_mfma_f32_16x16x32_bf16(al[i], bfr[j], acc[i][j], 0, 0, 0);
            }
        __syncthreads();
    }

    // epilogue: C/D layout col=lane&15, row=quad*4+reg
#pragma unroll
    for (int j = 0; j < 4; ++j) {
        const int col = bn + wc + j * 16 + mcol;
        float bs = 0.f;
        if (MODE == 1) bs = bias[col];
#pragma unroll
        for (int i = 0; i < 4; ++i)
#pragma unroll
            for (int rg = 0; rg < 4; ++rg) {
                const int rrow = bm + wr + i * 16 + quad * 4 + rg;
                if (MODE == 0) Cb[(size_t)rrow * N + col] = f2bf(acc[i][j][rg]);
                else           Cf[(size_t)rrow * N + col] = acc[i][j][rg] + bs;
            }
    }
}

// ---------------------------------------------------------------------------
// Attention (round-5 structure): bf16 MFMA QK^T + PV, one block per
// (b,h,8-row tile). K read from kv16 (stride 1536); epilogue writes split
// bf16 x_hi/x_lo for the split-A proj GEMM.
// ---------------------------------------------------------------------------
__global__ __launch_bounds__(256) void attn_kernel(
    const unsigned short* __restrict__ qb, const unsigned short* __restrict__ kv16,
    const unsigned short* __restrict__ vT,
    unsigned short* __restrict__ xh, unsigned short* __restrict__ xl)
{
    const int bid  = blockIdx.x;       // b*8*128 + h*128 + tile
    const int tile = bid & 127;
    const int h    = (bid >> 7) & 7;
    const int b    = bid >> 10;
    const int lq0  = tile * TQ;
    const int tid  = threadIdx.x;
    const int lane = tid & 63;
    const int wv   = tid >> 6;
    const int mcol = lane & 15;
    const int quad = lane >> 4;

    __shared__ __align__(16) float sP[TQ][1024];
    __shared__ __align__(16) unsigned short sPb[TQ][1032];
    __shared__ float rstat[6][TQ];

    // ---- QK^T via MFMA ----
    {
        const size_t qrow = ((size_t)(b * NT) + lq0 + (mcol & 7)) * 768 + h * 96 + quad * 8;
        const bf16x8 qa0 = *(const bf16x8*)&qb[qrow];
        const bf16x8 qa1 = *(const bf16x8*)&qb[qrow + 32];
        const bf16x8 qa2 = *(const bf16x8*)&qb[qrow + 64];

        for (int nt = wv * 16; nt < wv * 16 + 16; ++nt) {
            const int n0 = nt * 16;
            const size_t krow = ((size_t)(b * NK) + n0 + mcol) * 1536 + h * 96 + quad * 8;
            f32x4 d = {0.f, 0.f, 0.f, 0.f};
            d = __builtin_amdgcn_mfma_f32_16x16x32_bf16(qa0, *(const bf16x8*)&kv16[krow],      d, 0, 0, 0);
            d = __builtin_amdgcn_mfma_f32_16x16x32_bf16(qa1, *(const bf16x8*)&kv16[krow + 32], d, 0, 0, 0);
            d = __builtin_amdgcn_mfma_f32_16x16x32_bf16(qa2, *(const bf16x8*)&kv16[krow + 64], d, 0, 0, 0);
            if (quad < 2) {
#pragma unroll
                for (int rg = 0; rg < 4; ++rg)
                    sP[quad * 4 + rg][n0 + mcol] = d[rg] * SCALE_;
            }
        }
    }
    __syncthreads();

    // ---- split softmax stats; 32 threads per row ----
    const int r = tid >> 5, s = tid & 31;
    float* row = sP[r];

    float mx = -INFINITY;
    for (int j = 0; j < 32; ++j) {
        int n = s + 32 * j;
        if (n >= CLS_) mx = fmaxf(mx, row[n]);
    }
#pragma unroll
    for (int m = 1; m <= 16; m <<= 1) mx = fmaxf(mx, __shfl_xor(mx, m));
    if (s == 0) rstat[0][r] = mx;
    __syncthreads();

    const float pm = rstat[0][r];
    float sum = 0.f;
    for (int j = 0; j < 32; ++j) {
        int n = s + 32 * j;
        if (n >= CLS_) sum += __expf(row[n] - pm);
    }
#pragma unroll
    for (int m = 1; m <= 16; m <<= 1) sum += __shfl_xor(sum, m);
    if (s == 0) rstat[1][r] = sum;
    if (s == 1) {
        float cm = -INFINITY;
        for (int n = 0; n < CLS_; ++n) cm = fmaxf(cm, row[n]);
        float cs = 0.f;
        for (int n = 0; n < CLS_; ++n) cs += __expf(row[n] - cm);
        rstat[2][r] = cm; rstat[3][r] = cs;
    }
    __syncthreads();

    // ---- first-softmax probs + threefry mask ----
    {
        const float ips = 1.f / rstat[1][r];
        const float cm  = rstat[2][r];
        const float ics = 1.f / rstat[3][r];
        const uint32_t gbase =
            ((uint32_t)(b * H_ + h) * (uint32_t)L_ + (uint32_t)(lq0 + r + CLS_)) * (uint32_t)NK;
        for (int j = 0; j < 32; ++j) {
            int n = s + 32 * j;
            float l = row[n];
            float p = (n < CLS_) ? __expf(l - cm) * ics : __expf(l - pm) * ips;
            float u = jax_uniform(gbase + (uint32_t)n);
            if (u < 0.3f) p += NEG_;
            row[n] = p;
        }
    }
    __syncthreads();

    // ---- 2nd softmax: bf16 exp into sPb; 1/s2 folded into PV ----
    float mx2 = -INFINITY;
    for (int j = 0; j < 32; ++j) mx2 = fmaxf(mx2, row[s + 32 * j]);
#pragma unroll
    for (int m = 1; m <= 16; m <<= 1) mx2 = fmaxf(mx2, __shfl_xor(mx2, m));
    if (s == 0) rstat[4][r] = mx2;
    __syncthreads();

    const float m2 = rstat[4][r];
    float s2 = 0.f;
    for (int j = 0; j < 32; ++j) {
        int n = s + 32 * j;
        float e = __expf(row[n] - m2);
        sPb[r][n] = f2bf(e);
        s2 += e;
    }
#pragma unroll
    for (int m = 1; m <= 16; m <<= 1) s2 += __shfl_xor(s2, m);
    if (s == 0) rstat[5][r] = s2;
    __syncthreads();

    // ---- PV via MFMA ----
    {
        const int t0 = wv, t1 = wv + 4;
        const size_t vbase = ((size_t)(b * 8 + h)) * 96 * 1024;
        f32x4 a0 = {0.f, 0.f, 0.f, 0.f};
        f32x4 a1 = {0.f, 0.f, 0.f, 0.f};
        for (int k0 = 0; k0 < 1024; k0 += 32) {
            const bf16x8 pa = *(const bf16x8*)&sPb[mcol & 7][k0 + quad * 8];
            const size_t v0 = vbase + (size_t)(t0 * 16 + mcol) * 1024 + k0 + quad * 8;
            a0 = __builtin_amdgcn_mfma_f32_16x16x32_bf16(pa, *(const bf16x8*)&vT[v0], a0, 0, 0, 0);
            if (t1 < 6) {
                const size_t v1 = vbase + (size_t)(t1 * 16 + mcol) * 1024 + k0 + quad * 8;
                a1 = __builtin_amdgcn_mfma_f32_16x16x32_bf16(pa, *(const bf16x8*)&vT[v1], a1, 0, 0, 0);
            }
        }
        if (quad < 2) {
#pragma unroll
            for (int rg = 0; rg < 4; ++rg) {
                const int rw = quad * 4 + rg;
                const float inv = 1.f / rstat[5][rw];
                const size_t ob = ((size_t)(b * NT) + lq0 + rw) * 768 + h * 96;
                {
                    float v = a0[rg] * inv;
                    unsigned short hb = f2bf(v);
                    xh[ob + t0 * 16 + mcol] = hb;
                    xl[ob + t0 * 16 + mcol] = f2bf(v - __uint_as_float((uint32_t)hb << 16));
                }
                if (t1 < 6) {
                    float v = a1[rg] * inv;
                    unsigned short hb = f2bf(v);
                    xh[ob + t1 * 16 + mcol] = hb;
                    xl[ob + t1 * 16 + mcol] = f2bf(v - __uint_as_float((uint32_t)hb << 16));
                }
            }
        }
    }
}

// ---------------------------------------------------------------------------
extern "C" void kernel_launch(void* const* d_in, const int* in_sizes, int n_in,
                              void* d_out, int out_size, void* d_ws, size_t ws_size,
                              hipStream_t stream)
{
    const float* in_q   = (const float*)d_in[0];
    const float* in_k   = (const float*)d_in[1];
    const float* Wq     = (const float*)d_in[2];
    const float* Wkv    = (const float*)d_in[3];
    // d_in[4] = Wcls — unused (cls query rows are dropped by the reference)
    const float* Wproj  = (const float*)d_in[5];
    const float* bproj  = (const float*)d_in[6];
    float* out = (float*)d_out;

    // workspace layout (bf16 units); total 80.2 MB < 96 MB proven capacity
    unsigned short* ws16 = (unsigned short*)d_ws;
    unsigned short* Aq   = ws16;                  // 6291456
    unsigned short* Ak   = Aq   + 6291456;        // 6291456
    unsigned short* qb   = Ak   + 6291456;        // 6291456
    unsigned short* kv16 = qb   + 6291456;        // 12582912
    unsigned short* vT   = kv16 + 12582912;       // 6291456
    unsigned short* Wqt  = vT   + 6291456;        // 589824
    unsigned short* Wkvt = Wqt  + 589824;         // 1179648
    unsigned short* Wpt  = Wkvt + 1179648;        // 589824
    unsigned short* xh   = Aq;                    // reuse (dead after gemm_q)
    unsigned short* xl   = Ak;                    // reuse (dead after gemm_kv)

    dim3 blk(256);

    conv_bf16<<<6144, blk, 0, stream>>>(in_q, Aq, 1572864);
    conv_bf16<<<6144, blk, 0, stream>>>(in_k, Ak, 1572864);
    trw_bf16<<<dim3(24, 24), blk, 0, stream>>>(Wq,    Wqt,  768);
    trw_bf16<<<dim3(48, 24), blk, 0, stream>>>(Wkv,   Wkvt, 1536);
    trw_bf16<<<dim3(24, 24), blk, 0, stream>>>(Wproj, Wpt,  768);

    // qb = bf16(in_q @ Wq)
    mfma_gemm<0><<<dim3(6, 64), blk, 0, stream>>>(
        Aq, nullptr, Wqt, nullptr, qb, nullptr, 768, 768);

    // kv16 = bf16(in_k @ Wkv)
    mfma_gemm<0><<<dim3(12, 64), blk, 0, stream>>>(
        Ak, nullptr, Wkvt, nullptr, kv16, nullptr, 1536, 768);

    trv<<<1024, blk, 0, stream>>>(kv16, vT);

    attn_kernel<<<8192, blk, 0, stream>>>(qb, kv16, vT, xh, xl);

    // out = (xh + xl) @ Wproj + bproj   (split-A for fp32-grade accuracy)
    mfma_gemm<1><<<dim3(6, 64), blk, 0, stream>>>(
        xh, xl, Wpt, bproj, nullptr, out, 768, 768);
}